// Round 8
// baseline (282.262 us; speedup 1.0000x reference)
//
#include <hip/hip_runtime.h>

#define DEVI __device__ __forceinline__

constexpr int S = 8192, D = 1024, H = 16, HD = 64;
constexpr int NQKV = 3 * D;

typedef __attribute__((ext_vector_type(8))) __bf16 bf16x8;
typedef __attribute__((ext_vector_type(4))) __bf16 bf16x4;
typedef __attribute__((ext_vector_type(8))) unsigned short us8;
typedef __attribute__((ext_vector_type(4))) float f32x4;
typedef __attribute__((ext_vector_type(16))) float f32x16;

DEVI unsigned short f2b(float f) {
  unsigned int u = __float_as_uint(f);
  u += 0x7fff + ((u >> 16) & 1);   // RNE
  return (unsigned short)(u >> 16);
}

DEVI ushort4 cvt4(float4 v) {
  ushort4 r; r.x = f2b(v.x); r.y = f2b(v.y); r.z = f2b(v.z); r.w = f2b(v.w); return r;
}

DEVI void load_lds16b(const void* g, void* l) {
  __builtin_amdgcn_global_load_lds((const __attribute__((address_space(1))) void*)g,
                                   (__attribute__((address_space(3))) void*)l,
                                   16, 0, 0);
}

// ---------------- prep: fp32 -> bf16 casts + weight/bias concat ----------------
__global__ void prep_kernel(const float4* __restrict__ x,
                            const float4* __restrict__ Wq, const float4* __restrict__ Wk,
                            const float4* __restrict__ Wv, const float4* __restrict__ Wo,
                            const float4* __restrict__ bq, const float4* __restrict__ bk,
                            const float4* __restrict__ bv,
                            ushort4* __restrict__ xb, ushort4* __restrict__ wqkv,
                            ushort4* __restrict__ wob, float4* __restrict__ biasq)
{
  constexpr int NX = S * D / 4;
  constexpr int NW = D * D / 4;
  constexpr int NB = D / 4;
  constexpr int TOT = NX + 4 * NW + 3 * NB;
  for (int i = blockIdx.x * blockDim.x + threadIdx.x; i < TOT; i += gridDim.x * blockDim.x) {
    if (i < NX) {
      xb[i] = cvt4(x[i]);
    } else if (i < NX + 3 * NW) {
      int j = i - NX;
      const float4* src = (j < NW) ? Wq : ((j < 2 * NW) ? Wk : Wv);
      int jj = (j < NW) ? j : ((j < 2 * NW) ? j - NW : j - 2 * NW);
      wqkv[j] = cvt4(src[jj]);
    } else if (i < NX + 4 * NW) {
      int j = i - NX - 3 * NW;
      wob[j] = cvt4(Wo[j]);
    } else {
      int j = i - NX - 4 * NW;
      const float4* src = (j < NB) ? bq : ((j < 2 * NB) ? bk : bv);
      int jj = (j < NB) ? j : ((j < 2 * NB) ? j - NB : j - 2 * NB);
      biasq[j] = src[jj];
    }
  }
}

// ---------------- NT GEMM: C[m][n] = sum_k A[m][k]*B[n][k] + bias[n] ----------------
template<int LDC, bool OUT_BF16>
__global__ __launch_bounds__(256)
void gemm_nt(const unsigned short* __restrict__ A,
             const unsigned short* __restrict__ B,
             const float* __restrict__ bias,
             void* __restrict__ C, int K)
{
  __shared__ __align__(16) unsigned short As[2][128 * 32];
  __shared__ __align__(16) unsigned short Bs[2][128 * 32];
  const int tid = threadIdx.x;
  const int wave = tid >> 6, lane = tid & 63;
  const int quad = lane >> 4, l15 = lane & 15;
  const int m0 = blockIdx.x * 128, n0 = blockIdx.y * 128;
  const int wr = wave >> 1, wc = wave & 1;

  const f32x4 fzero = {0.f, 0.f, 0.f, 0.f};
  f32x4 acc[4][4];
#pragma unroll
  for (int i = 0; i < 4; ++i)
#pragma unroll
    for (int j = 0; j < 4; ++j) acc[i][j] = fzero;

  const int segr = lane >> 2;
  const int cpst = lane & 3;

#define GST(k0_, b_)                                                              \
  {                                                                               \
    _Pragma("unroll")                                                             \
    for (int j = 0; j < 4; ++j) {                                                 \
      const int s = wave * 4 + j;                                                 \
      const int s7 = s & 7;                                                       \
      const int r = s7 * 16 + segr;                                               \
      const int c = cpst ^ ((r >> 1) & 3);                                        \
      const unsigned short* g = (s < 8)                                           \
        ? A + (size_t)(m0 + r) * K + (k0_) + c * 8                                \
        : B + (size_t)(n0 + r) * K + (k0_) + c * 8;                               \
      unsigned short* l = ((s < 8) ? As[b_] : Bs[b_]) + s7 * 512;                 \
      load_lds16b(g, l);                                                          \
    }                                                                             \
  }

  GST(0, 0);
  int b = 0;
  for (int k0 = 0; k0 < K; k0 += 32, b ^= 1) {
    __syncthreads();
    if (k0 + 32 < K) GST(k0 + 32, b ^ 1);

    bf16x8 af[4], bfr[4];
#pragma unroll
    for (int it = 0; it < 4; ++it) {
      const int r = wr * 64 + it * 16 + l15;
      const int cp = quad ^ ((r >> 1) & 3);
      af[it] = *(const bf16x8*)&As[b][r * 32 + cp * 8];
    }
#pragma unroll
    for (int jt = 0; jt < 4; ++jt) {
      const int r = wc * 64 + jt * 16 + l15;
      const int cp = quad ^ ((r >> 1) & 3);
      bfr[jt] = *(const bf16x8*)&Bs[b][r * 32 + cp * 8];
    }
#pragma unroll
    for (int it = 0; it < 4; ++it)
#pragma unroll
      for (int jt = 0; jt < 4; ++jt)
        acc[it][jt] = __builtin_amdgcn_mfma_f32_16x16x32_bf16(af[it], bfr[jt], acc[it][jt], 0, 0, 0);
  }
#undef GST

#pragma unroll
  for (int it = 0; it < 4; ++it)
#pragma unroll
    for (int jt = 0; jt < 4; ++jt) {
      const int col = n0 + wc * 64 + jt * 16 + l15;
      const float bv = bias[col];
#pragma unroll
      for (int i = 0; i < 4; ++i) {
        const int row = m0 + wr * 64 + it * 16 + quad * 4 + i;
        const float v = acc[it][jt][i] + bv;
        if constexpr (OUT_BF16)
          ((unsigned short*)C)[(size_t)row * LDC + col] = f2b(v);
        else
          ((float*)C)[(size_t)row * LDC + col] = v;
      }
    }
}

// ---------------- transpose V: qkv[key][2048+h*64+d] -> vtb[h][d][key] ----------------
__global__ __launch_bounds__(256)
void transpose_v(const unsigned short* __restrict__ qkv, unsigned short* __restrict__ vtb)
{
  __shared__ unsigned short T[64 * 72];
  const int tid = threadIdx.x;
  const int kb = blockIdx.x, h = blockIdx.y;
  const unsigned short* Vp = qkv + 2 * D + h * HD;
  const int key = tid >> 3, sg = tid & 7;
#pragma unroll
  for (int r = 0; r < 2; ++r) {
    us8 v = *(const us8*)(Vp + (size_t)(kb * 64 + key + r * 32) * NQKV + sg * 8);
    unsigned short* dst = &T[sg * 8 * 72 + key + r * 32];
#pragma unroll
    for (int j = 0; j < 8; ++j) dst[j * 72] = v[j];
  }
  __syncthreads();
  const int d = tid >> 2, kc = tid & 3;
  us8* outp = (us8*)(vtb + (size_t)h * HD * S + (size_t)d * S + kb * 64 + kc * 16);
  outp[0] = *(const us8*)&T[d * 72 + kc * 16];
  outp[1] = *(const us8*)&T[d * 72 + kc * 16 + 8];
}

// ---------------- fused sliding-window attention (v8) ----------------
// 32x32x16 MFMA; P stays in REGISTERS: S^T C-layout -> PV A-layout needs only
// a cross-half (lane^32) exchange of packed bf16 pairs (8 shfl per 32-key
// block). No Ps LDS (32 KB total -> 4 blocks/CU). K/V^T DMA double-buffered.
__global__ __launch_bounds__(256)
void attn_fused(const unsigned short* __restrict__ qkv,
                const unsigned short* __restrict__ vtb,
                unsigned short* __restrict__ attnb)
{
  __shared__ __align__(16) unsigned short Ks[2][64 * 64];   // [key][slot], slot = dc ^ (key&7)
  __shared__ __align__(16) unsigned short Vt[2][64 * 64];   // [d][slot],  slot = kc ^ (d&7)
  const int tid = threadIdx.x;
  const int wave = tid >> 6, lane = tid & 63;
  const int l31 = lane & 31, hi = lane >> 5;

  // XCD swizzle: xcd = linear_block_id % 8; each XCD gets 2 heads x all q.
  const int id = blockIdx.x + 64 * blockIdx.y;        // 0..1023
  const int h  = (id & 7) * 2 + ((id >> 3) >> 6);
  const int q0 = ((id >> 3) & 63) * 128;
  const int wq0 = q0 + wave * 32;

  const unsigned short* Qp = qkv + h * HD;
  const unsigned short* Kp = qkv + D + h * HD;
  const unsigned short* Vh = vtb + (size_t)h * HD * S;   // [d][key]

  // Q fragments (B-operand): lane holds Q[q=l31][m*16 + hi*8 + j]
  bf16x8 qf[4];
#pragma unroll
  for (int m = 0; m < 4; ++m)
    qf[m] = *(const bf16x8*)(Qp + (size_t)(wq0 + l31) * NQKV + m * 16 + hi * 8);

  f32x16 o[2];
#pragma unroll
  for (int n = 0; n < 2; ++n)
#pragma unroll
    for (int r = 0; r < 16; ++r) o[n][r] = 0.f;
  float lr = 0.f;

  const int ks = (q0 >= 512) ? (q0 - 512) : 0;
  const int ke = (q0 + 640 < S) ? (q0 + 640) : S;

  const int srow = tid >> 3;
  const int sg   = tid & 7;
  const int scol = sg ^ (srow & 7);

#define STAGE(kt_, b_)                                                            \
  {                                                                               \
    _Pragma("unroll")                                                             \
    for (int r = 0; r < 2; ++r) {                                                 \
      load_lds16b(Kp + (size_t)((kt_) + srow + r * 32) * NQKV + scol * 8,         \
                  &Ks[b_][(size_t)tid * 8 + r * 2048]);                           \
      load_lds16b(Vh + (size_t)(srow + r * 32) * S + (kt_) + scol * 8,            \
                  &Vt[b_][(size_t)tid * 8 + r * 2048]);                           \
    }                                                                             \
  }

  STAGE(ks, 0);

  constexpr float L2E8 = 0.18033688011112042f;  // log2(e)/8

  int b = 0;
  for (int kt = ks; kt < ke; kt += 64, b ^= 1) {
    __syncthreads();
    if (kt + 64 < ke) STAGE(kt + 64, b ^ 1);

    if (kt + 63 >= wq0 - 512 && kt <= wq0 + 31 + 511) {
      bf16x8 af[2][2];           // PV A-fragments, [kb2][m]
      bool act[2];

      // ---- Phase A: S^T = K·Q^T, exp, pack P into A-fragments via lane^32 swap ----
#pragma unroll
      for (int kb2 = 0; kb2 < 2; ++kb2) {
        const int C0 = kt + kb2 * 32;
        act[kb2] = (C0 + 31 >= wq0 - 512) && (C0 <= wq0 + 31 + 511);
        if (!act[kb2]) continue;

        bf16x8 kf[4];
#pragma unroll
        for (int m = 0; m < 4; ++m)
          kf[m] = *(const bf16x8*)&Ks[b][(kb2 * 32 + l31) * 64 + ((m * 2 + hi) ^ (l31 & 7)) * 8];
        f32x16 z;
#pragma unroll
        for (int r = 0; r < 16; ++r) z[r] = 0.f;
#pragma unroll
        for (int m = 0; m < 4; ++m)
          z = __builtin_amdgcn_mfma_f32_32x32x16_bf16(kf[m], qf[m], z, 0, 0, 0);

        float p[16];
        const bool full = (C0 >= wq0 - 481) && (C0 <= wq0 + 480);
        if (full) {
#pragma unroll
          for (int r = 0; r < 16; ++r) p[r] = __builtin_amdgcn_exp2f(z[r] * L2E8);
        } else {
          // key = C0 + (r&3) + 8*(r>>2) + 4*hi ; q = wq0 + l31
          const int base = C0 + 4 * hi - (wq0 + l31) + 512;
#pragma unroll
          for (int r = 0; r < 16; ++r) {
            const int u = base + (r & 3) + 8 * (r >> 2);
            p[r] = ((unsigned)u < 1024u) ? __builtin_amdgcn_exp2f(z[r] * L2E8) : 0.f;
          }
        }
#pragma unroll
        for (int r = 0; r < 16; ++r) lr += p[r];

        // pack groups of 4 consecutive keys -> 8 uints (own keys 8g+4hi+0..3)
        unsigned u[8], ex[8];
#pragma unroll
        for (int g = 0; g < 4; ++g) {
          f32x4 pv4 = {p[4 * g], p[4 * g + 1], p[4 * g + 2], p[4 * g + 3]};
          bf16x4 b4 = __builtin_convertvector(pv4, bf16x4);
          unsigned uu[2];
          __builtin_memcpy(uu, &b4, 8);
          u[2 * g] = uu[0];
          u[2 * g + 1] = uu[1];
        }
#pragma unroll
        for (int j = 0; j < 8; ++j) ex[j] = (unsigned)__shfl_xor((int)u[j], 32);

        // A-frag m covers keys kb2*32 + m*16 + hi*8 + (0..7):
        //   jj0-3 = group G=2m+hi, sub 0 (hi=0 own / hi=1 partner)
        //   jj4-7 = group G,      sub 1 (hi=0 partner / hi=1 own)
#pragma unroll
        for (int m = 0; m < 2; ++m) {
          unsigned w[4];
          w[0] = hi ? ex[4 * m + 2] : u[4 * m];
          w[1] = hi ? ex[4 * m + 3] : u[4 * m + 1];
          w[2] = hi ? u[4 * m + 2] : ex[4 * m];
          w[3] = hi ? u[4 * m + 3] : ex[4 * m + 1];
          __builtin_memcpy(&af[kb2][m], w, 16);
        }
      }

      // ---- Phase B: O += P·V ----
#pragma unroll
      for (int kb2 = 0; kb2 < 2; ++kb2) {
        if (!act[kb2]) continue;
#pragma unroll
        for (int m = 0; m < 2; ++m) {
          const int s = kb2 * 2 + m;
#pragma unroll
          for (int n = 0; n < 2; ++n) {
            const int d = n * 32 + l31;
            const bf16x8 vf = *(const bf16x8*)&Vt[b][d * 64 + ((s * 2 + hi) ^ (d & 7)) * 8];
            o[n] = __builtin_amdgcn_mfma_f32_32x32x16_bf16(af[kb2][m], vf, o[n], 0, 0, 0);
          }
        }
      }
    }
  }
#undef STAGE

  // epilogue: fold l across hi halves, redistribute, tail blend, store
  lr += __shfl_xor(lr, 32);
#pragma unroll
  for (int r = 0; r < 16; ++r) {
    const int qr = (r & 3) + 8 * (r >> 2) + 4 * hi;
    const float lq = __shfl(lr, qr);
    const int qa = wq0 + qr;
    const float w = (qa >= S - 128) ? (1.0f + (float)(qa - (S - 128)) * (1.0f / 127.0f)) : 1.0f;
    const float scl = w / lq;
#pragma unroll
    for (int n = 0; n < 2; ++n)
      ((__bf16*)attnb)[(size_t)qa * D + h * HD + n * 32 + l31] = (__bf16)(o[n][r] * scl);
  }
}

// ---------------- launch ----------------
extern "C" void kernel_launch(void* const* d_in, const int* in_sizes, int n_in,
                              void* d_out, int out_size, void* d_ws, size_t ws_size,
                              hipStream_t stream)
{
  const float* x  = (const float*)d_in[0];
  const float* Wq = (const float*)d_in[1];
  const float* Wk = (const float*)d_in[2];
  const float* Wv = (const float*)d_in[3];
  const float* Wo = (const float*)d_in[4];
  const float* bq = (const float*)d_in[5];
  const float* bk = (const float*)d_in[6];
  const float* bv = (const float*)d_in[7];
  const float* bo = (const float*)d_in[8];

  char* ws = (char*)d_ws;
  unsigned short* xb    = (unsigned short*)(ws);              // 16 MB (reused as vtb)
  unsigned short* wqkv  = (unsigned short*)(ws + 16777216);   //  6 MB
  unsigned short* wob   = (unsigned short*)(ws + 23068672);   //  2 MB
  float*          biasq = (float*)         (ws + 25165824);   // 12 KB
  unsigned short* qkv   = (unsigned short*)(ws + 25178112);   // 48 MB
  unsigned short* attnb = (unsigned short*)(ws + 75509760);   // 16 MB
  unsigned short* vtb   = xb;                                 // xb dead after QKV GEMM

  prep_kernel<<<2048, 256, 0, stream>>>((const float4*)x, (const float4*)Wq, (const float4*)Wk,
                                        (const float4*)Wv, (const float4*)Wo, (const float4*)bq,
                                        (const float4*)bk, (const float4*)bv,
                                        (ushort4*)xb, (ushort4*)wqkv, (ushort4*)wob, (float4*)biasq);

  gemm_nt<NQKV, true><<<dim3(64, 24), 256, 0, stream>>>(xb, wqkv, biasq, (void*)qkv, D);
  transpose_v<<<dim3(S / 64, H), 256, 0, stream>>>(qkv, vtb);
  attn_fused<<<dim3(S / 128, H), 256, 0, stream>>>(qkv, vtb, attnb);
  gemm_nt<D, false><<<dim3(64, 8), 256, 0, stream>>>(attnb, wob, bo, d_out, D);
}